// Round 13
// baseline (1801.250 us; speedup 1.0000x reference)
//
#include <hip/hip_runtime.h>
#include <hip/hip_bf16.h>

// R12 (resubmit — broker timeout): attribution + MLP restructure.
//  - encode_hash split into 12 per-level dispatches (same total work) so the
//    smaller kernels become visible in top-5 counters.
//  - encode_dense unchanged from R9 (rows 0..7 of hT).
//  - MLP rebuilt: weights in LDS (broadcast ds_read_b128), layers j-rolled /
//    k-unrolled so all activation indexing is static (no LDS columns, no
//    scratch). L1 fused into L2 accumulation; L3 streams to out.
//    A/B: mlp_one (1 pt/thread, DS-bound) on half the points,
//         mlp_two (2 pts/thread, weight reuse -> FMA-bound) on the other half.

#define NLVL 16
#define TSZ   524288u
#define TMASK 524287u
#define PR1 2654435761u
#define PR2 805459861u

__device__ __constant__ int kResC[NLVL] = {16,24,36,54,81,121,182,273,410,615,922,1383,2075,3113,4670,7006};
constexpr int kRes[NLVL] = {16,24,36,54,81,121,182,273,410,615,922,1383,2075,3113,4670,7006};
constexpr bool kDense[NLVL] = {true,true,true,true,false,false,false,false,
                               false,false,false,false,false,false,false,false};

__device__ __forceinline__ void trilerp(const float2 f0, const float2 f1, const float2 f2, const float2 f3,
                                        const float2 f4, const float2 f5, const float2 f6, const float2 f7,
                                        float wx, float wy, float wz, float& a0, float& a1)
{
    const float ax = 1.f - wx, ay = 1.f - wy, az = 1.f - wz;
    const float g00 = ax * ay, g01 = ax * wy, g10 = wx * ay, g11 = wx * wy;
    float s0 = 0.f, s1 = 0.f, v;
    v = g00 * az; s0 = fmaf(v, f0.x, s0); s1 = fmaf(v, f0.y, s1);
    v = g00 * wz; s0 = fmaf(v, f1.x, s0); s1 = fmaf(v, f1.y, s1);
    v = g01 * az; s0 = fmaf(v, f2.x, s0); s1 = fmaf(v, f2.y, s1);
    v = g01 * wz; s0 = fmaf(v, f3.x, s0); s1 = fmaf(v, f3.y, s1);
    v = g10 * az; s0 = fmaf(v, f4.x, s0); s1 = fmaf(v, f4.y, s1);
    v = g10 * wz; s0 = fmaf(v, f5.x, s0); s1 = fmaf(v, f5.y, s1);
    v = g11 * az; s0 = fmaf(v, f6.x, s0); s1 = fmaf(v, f6.y, s1);
    v = g11 * wz; s0 = fmaf(v, f7.x, s0); s1 = fmaf(v, f7.y, s1);
    a0 = s0; a1 = s1;
}

__device__ __forceinline__ void hash_point(float px, float py, float pz, float res,
                                           const float2* __restrict__ tl,
                                           float& a0, float& a1)
{
    const float fx = px * res, fy = py * res, fz = pz * res;
    const float bx = floorf(fx), by = floorf(fy), bz = floorf(fz);
    const float wx = fx - bx, wy = fy - by, wz = fz - bz;
    const unsigned cx = (unsigned)bx, cy = (unsigned)by, cz = (unsigned)bz;
    const unsigned hy0 = cy * PR1, hy1 = hy0 + PR1;
    const unsigned hz0 = cz * PR2, hz1 = hz0 + PR2;
    const unsigned e00 = hy0 ^ hz0, e01 = hy0 ^ hz1, e10 = hy1 ^ hz0, e11 = hy1 ^ hz1;
    const unsigned x1 = cx + 1u;
    const float2 f0 = tl[(cx ^ e00) & TMASK];
    const float2 f1 = tl[(cx ^ e01) & TMASK];
    const float2 f2 = tl[(cx ^ e10) & TMASK];
    const float2 f3 = tl[(cx ^ e11) & TMASK];
    const float2 f4 = tl[(x1 ^ e00) & TMASK];
    const float2 f5 = tl[(x1 ^ e01) & TMASK];
    const float2 f6 = tl[(x1 ^ e10) & TMASK];
    const float2 f7 = tl[(x1 ^ e11) & TMASK];
    trilerp(f0,f1,f2,f3,f4,f5,f6,f7, wx,wy,wz, a0,a1);
}

template<int RES>
__device__ __forceinline__ void dense_point(float px, float py, float pz,
                                            const float2* __restrict__ tl,
                                            float& a0, float& a1)
{
    const float res = (float)RES;
    const float fx = px * res, fy = py * res, fz = pz * res;
    const float bx = floorf(fx), by = floorf(fy), bz = floorf(fz);
    const float wx = fx - bx, wy = fy - by, wz = fz - bz;
    const unsigned cx = (unsigned)bx, cy = (unsigned)by, cz = (unsigned)bz;
    const unsigned s = RES + 1u, s2 = s * s;
    const unsigned b = cx + cy * s + cz * s2;
    const float2 f0 = tl[b];
    const float2 f1 = tl[b + s2];
    const float2 f2 = tl[b + s];
    const float2 f3 = tl[b + s + s2];
    const float2 f4 = tl[b + 1u];
    const float2 f5 = tl[b + 1u + s2];
    const float2 f6 = tl[b + 1u + s];
    const float2 f7 = tl[b + 1u + s + s2];
    trilerp(f0,f1,f2,f3,f4,f5,f6,f7, wx,wy,wz, a0,a1);
}

// ---------------- dense levels 0-3 (unchanged from R9) ----------------
__global__ __launch_bounds__(256)
void encode_dense(const float* __restrict__ x, const float* __restrict__ table,
                  float* __restrict__ hT, int n)
{
    const int i = blockIdx.x * 256 + threadIdx.x;
    if (i >= n) return;
    const float px = x[3*i+0], py = x[3*i+1], pz = x[3*i+2];
    const float2* tb = (const float2*)table;
    float a0, a1;
    dense_point<16>(px,py,pz, tb,                 a0,a1);
    hT[i] = a0;                     hT[(size_t)n + i] = a1;
    dense_point<24>(px,py,pz, tb + TSZ,           a0,a1);
    hT[(size_t)2*n + i] = a0;       hT[(size_t)3*n + i] = a1;
    dense_point<36>(px,py,pz, tb + 2*(size_t)TSZ, a0,a1);
    hT[(size_t)4*n + i] = a0;       hT[(size_t)5*n + i] = a1;
    dense_point<54>(px,py,pz, tb + 3*(size_t)TSZ, a0,a1);
    hT[(size_t)6*n + i] = a0;       hT[(size_t)7*n + i] = a1;
}

// ---------------- one hashed level per dispatch (body == R9's encode_hash) ----------------
__global__ __launch_bounds__(256)
void encode_hash_lvl(const float* __restrict__ x, const float* __restrict__ table,
                     float* __restrict__ hT, int n, int l)
{
    const float res = (float)kResC[l];
    const float2* __restrict__ tl = (const float2*)table + (size_t)l * TSZ;
    float* __restrict__ r0 = hT + (size_t)(2*l) * n;
    float* __restrict__ r1 = r0 + n;

    const int t  = threadIdx.x;
    const int i0 = (blockIdx.x << 10) + (t << 2);   // 1024 pts/block, 4/thread

    if (i0 + 3 < n) {
        const float4* __restrict__ xv = reinterpret_cast<const float4*>(x + (size_t)3 * i0);
        const float4 A = xv[0], B = xv[1], C = xv[2];
        const float px[4] = {A.x, A.w, B.z, C.y};
        const float py[4] = {A.y, B.x, B.w, C.z};
        const float pz[4] = {A.z, B.y, C.x, C.w};

        unsigned idx[4][8];
        float wx[4], wy[4], wz[4];
#pragma unroll
        for (int p = 0; p < 4; ++p) {
            const float fx = px[p]*res, fy = py[p]*res, fz = pz[p]*res;
            const float bx = floorf(fx), by = floorf(fy), bz = floorf(fz);
            wx[p] = fx - bx; wy[p] = fy - by; wz[p] = fz - bz;
            const unsigned cx = (unsigned)bx, cy = (unsigned)by, cz = (unsigned)bz;
            const unsigned hy0 = cy * PR1, hy1 = hy0 + PR1;
            const unsigned hz0 = cz * PR2, hz1 = hz0 + PR2;
            const unsigned e00 = hy0 ^ hz0, e01 = hy0 ^ hz1, e10 = hy1 ^ hz0, e11 = hy1 ^ hz1;
            const unsigned x1c = cx + 1u;
            idx[p][0] = (cx  ^ e00) & TMASK;  idx[p][1] = (cx  ^ e01) & TMASK;
            idx[p][2] = (cx  ^ e10) & TMASK;  idx[p][3] = (cx  ^ e11) & TMASK;
            idx[p][4] = (x1c ^ e00) & TMASK;  idx[p][5] = (x1c ^ e01) & TMASK;
            idx[p][6] = (x1c ^ e10) & TMASK;  idx[p][7] = (x1c ^ e11) & TMASK;
        }
        float2 f[4][8];
#pragma unroll
        for (int p = 0; p < 4; ++p)
#pragma unroll
            for (int c = 0; c < 8; ++c) f[p][c] = tl[idx[p][c]];

        float o0[4], o1[4];
#pragma unroll
        for (int p = 0; p < 4; ++p)
            trilerp(f[p][0],f[p][1],f[p][2],f[p][3],f[p][4],f[p][5],f[p][6],f[p][7],
                    wx[p],wy[p],wz[p], o0[p],o1[p]);

        *reinterpret_cast<float4*>(r0 + i0) = make_float4(o0[0],o0[1],o0[2],o0[3]);
        *reinterpret_cast<float4*>(r1 + i0) = make_float4(o1[0],o1[1],o1[2],o1[3]);
    } else {
#pragma unroll
        for (int p = 0; p < 4; ++p) {
            const int i = i0 + p;
            if (i >= n) break;
            const float qx = x[3*i+0], qy = x[3*i+1], qz = x[3*i+2];
            float a0, a1;
            hash_point(qx,qy,qz, res, tl, a0,a1);
            r0[i] = a0; r1[i] = a1;
        }
    }
}

// ---------------- MLP variant A: 1 point/thread ----------------
__global__ __launch_bounds__(256, 3)
void mlp_one(const float* __restrict__ hT,
             const float* __restrict__ W1,
             const float* __restrict__ W2,
             const float* __restrict__ W3,
             float* __restrict__ out, int n, int base)
{
    __shared__ float sW1[32 * 64];   //  8 KB
    __shared__ float sW2[64 * 64];   // 16 KB
    __shared__ float sW3[64 * 16];   //  4 KB
    const int t = threadIdx.x;
#pragma unroll
    for (int r = 0; r < 8; ++r)  sW1[r * 256 + t] = W1[r * 256 + t];
#pragma unroll
    for (int r = 0; r < 16; ++r) sW2[r * 256 + t] = W2[r * 256 + t];
#pragma unroll
    for (int r = 0; r < 4; ++r)  sW3[r * 256 + t] = W3[r * 256 + t];
    __syncthreads();

    const int i = base + blockIdx.x * 256 + t;
    if (i >= n) return;

    float h[32];
#pragma unroll
    for (int f = 0; f < 32; ++f) h[f] = hT[(size_t)f * n + i];

    float h2[64];
#pragma unroll
    for (int j = 0; j < 64; ++j) h2[j] = 0.f;

    for (int jg = 0; jg < 16; ++jg) {            // rolled: 16 iters
        float g[4] = {0.f, 0.f, 0.f, 0.f};
        const float4* __restrict__ w1p = reinterpret_cast<const float4*>(sW1) + jg;
#pragma unroll
        for (int k = 0; k < 32; ++k) {
            const float4 w = w1p[k * 16];        // ds_read_b128, imm offset k*256
            g[0] = fmaf(h[k], w.x, g[0]);
            g[1] = fmaf(h[k], w.y, g[1]);
            g[2] = fmaf(h[k], w.z, g[2]);
            g[3] = fmaf(h[k], w.w, g[3]);
        }
#pragma unroll
        for (int c = 0; c < 4; ++c) g[c] = fmaxf(g[c], 0.f);
#pragma unroll
        for (int c = 0; c < 4; ++c) {
            const float4* __restrict__ w2p = reinterpret_cast<const float4*>(&sW2[(jg * 4 + c) * 64]);
            const float gc = g[c];
#pragma unroll
            for (int q = 0; q < 16; ++q) {
                const float4 w = w2p[q];
                h2[4*q+0] = fmaf(gc, w.x, h2[4*q+0]);
                h2[4*q+1] = fmaf(gc, w.y, h2[4*q+1]);
                h2[4*q+2] = fmaf(gc, w.z, h2[4*q+2]);
                h2[4*q+3] = fmaf(gc, w.w, h2[4*q+3]);
            }
        }
    }
#pragma unroll
    for (int j = 0; j < 64; ++j) h2[j] = fmaxf(h2[j], 0.f);

    for (int j3 = 0; j3 < 4; ++j3) {             // rolled: 4 iters
        float o[4] = {0.f, 0.f, 0.f, 0.f};
        const float4* __restrict__ w3p = reinterpret_cast<const float4*>(sW3) + j3;
#pragma unroll
        for (int k = 0; k < 64; ++k) {
            const float4 w = w3p[k * 4];         // imm offset k*64
            o[0] = fmaf(h2[k], w.x, o[0]);
            o[1] = fmaf(h2[k], w.y, o[1]);
            o[2] = fmaf(h2[k], w.z, o[2]);
            o[3] = fmaf(h2[k], w.w, o[3]);
        }
        *reinterpret_cast<float4*>(out + (size_t)i * 16 + j3 * 4) = make_float4(o[0], o[1], o[2], o[3]);
    }
}

// ---------------- MLP variant B: 2 points/thread (weight reuse) ----------------
__global__ __launch_bounds__(256, 2)
void mlp_two(const float* __restrict__ hT,
             const float* __restrict__ W1,
             const float* __restrict__ W2,
             const float* __restrict__ W3,
             float* __restrict__ out, int n)
{
    __shared__ float sW1[32 * 64];
    __shared__ float sW2[64 * 64];
    __shared__ float sW3[64 * 16];
    const int t = threadIdx.x;
#pragma unroll
    for (int r = 0; r < 8; ++r)  sW1[r * 256 + t] = W1[r * 256 + t];
#pragma unroll
    for (int r = 0; r < 16; ++r) sW2[r * 256 + t] = W2[r * 256 + t];
#pragma unroll
    for (int r = 0; r < 4; ++r)  sW3[r * 256 + t] = W3[r * 256 + t];
    __syncthreads();

    const int ia = blockIdx.x * 512 + t;   // grid sized so ia+256 < region end
    const int ib = ia + 256;

    float ha[32], hb[32];
#pragma unroll
    for (int f = 0; f < 32; ++f) { ha[f] = hT[(size_t)f * n + ia]; hb[f] = hT[(size_t)f * n + ib]; }

    float h2a[64], h2b[64];
#pragma unroll
    for (int j = 0; j < 64; ++j) { h2a[j] = 0.f; h2b[j] = 0.f; }

    for (int jg = 0; jg < 16; ++jg) {
        float ga[4] = {0.f,0.f,0.f,0.f}, gb[4] = {0.f,0.f,0.f,0.f};
        const float4* __restrict__ w1p = reinterpret_cast<const float4*>(sW1) + jg;
#pragma unroll
        for (int k = 0; k < 32; ++k) {
            const float4 w = w1p[k * 16];        // one ds_read feeds 8 FMAs
            ga[0] = fmaf(ha[k], w.x, ga[0]);  gb[0] = fmaf(hb[k], w.x, gb[0]);
            ga[1] = fmaf(ha[k], w.y, ga[1]);  gb[1] = fmaf(hb[k], w.y, gb[1]);
            ga[2] = fmaf(ha[k], w.z, ga[2]);  gb[2] = fmaf(hb[k], w.z, gb[2]);
            ga[3] = fmaf(ha[k], w.w, ga[3]);  gb[3] = fmaf(hb[k], w.w, gb[3]);
        }
#pragma unroll
        for (int c = 0; c < 4; ++c) { ga[c] = fmaxf(ga[c], 0.f); gb[c] = fmaxf(gb[c], 0.f); }
#pragma unroll
        for (int c = 0; c < 4; ++c) {
            const float4* __restrict__ w2p = reinterpret_cast<const float4*>(&sW2[(jg * 4 + c) * 64]);
            const float gca = ga[c], gcb = gb[c];
#pragma unroll
            for (int q = 0; q < 16; ++q) {
                const float4 w = w2p[q];
                h2a[4*q+0] = fmaf(gca, w.x, h2a[4*q+0]);  h2b[4*q+0] = fmaf(gcb, w.x, h2b[4*q+0]);
                h2a[4*q+1] = fmaf(gca, w.y, h2a[4*q+1]);  h2b[4*q+1] = fmaf(gcb, w.y, h2b[4*q+1]);
                h2a[4*q+2] = fmaf(gca, w.z, h2a[4*q+2]);  h2b[4*q+2] = fmaf(gcb, w.z, h2b[4*q+2]);
                h2a[4*q+3] = fmaf(gca, w.w, h2a[4*q+3]);  h2b[4*q+3] = fmaf(gcb, w.w, h2b[4*q+3]);
            }
        }
    }
#pragma unroll
    for (int j = 0; j < 64; ++j) { h2a[j] = fmaxf(h2a[j], 0.f); h2b[j] = fmaxf(h2b[j], 0.f); }

    for (int j3 = 0; j3 < 4; ++j3) {
        float oa[4] = {0.f,0.f,0.f,0.f}, ob[4] = {0.f,0.f,0.f,0.f};
        const float4* __restrict__ w3p = reinterpret_cast<const float4*>(sW3) + j3;
#pragma unroll
        for (int k = 0; k < 64; ++k) {
            const float4 w = w3p[k * 4];
            oa[0] = fmaf(h2a[k], w.x, oa[0]);  ob[0] = fmaf(h2b[k], w.x, ob[0]);
            oa[1] = fmaf(h2a[k], w.y, oa[1]);  ob[1] = fmaf(h2b[k], w.y, ob[1]);
            oa[2] = fmaf(h2a[k], w.z, oa[2]);  ob[2] = fmaf(h2b[k], w.z, ob[2]);
            oa[3] = fmaf(h2a[k], w.w, oa[3]);  ob[3] = fmaf(h2b[k], w.w, ob[3]);
        }
        *reinterpret_cast<float4*>(out + (size_t)ia * 16 + j3 * 4) = make_float4(oa[0], oa[1], oa[2], oa[3]);
        *reinterpret_cast<float4*>(out + (size_t)ib * 16 + j3 * 4) = make_float4(ob[0], ob[1], ob[2], ob[3]);
    }
}

// ---------------- fallback: known-correct fused kernel ----------------
__global__ __launch_bounds__(256)
void ngp_fused_kernel(const float* __restrict__ x,
                      const float* __restrict__ table,
                      const float* __restrict__ W1,
                      const float* __restrict__ W2,
                      const float* __restrict__ W3,
                      float* __restrict__ out,
                      int n)
{
    __shared__ float hS[32 * 256];
    const int t = threadIdx.x;
    const int i = blockIdx.x * 256 + t;
    if (i >= n) return;
    const float px = x[3*i+0], py = x[3*i+1], pz = x[3*i+2];

    float h[32];
#pragma unroll
    for (int l = 0; l < NLVL; ++l) {
        float a0, a1;
        if (kDense[l]) {
            const int r = kRes[l];
            if (r == 16) dense_point<16>(px,py,pz,(const float2*)table+(size_t)l*TSZ,a0,a1);
            else if (r == 24) dense_point<24>(px,py,pz,(const float2*)table+(size_t)l*TSZ,a0,a1);
            else if (r == 36) dense_point<36>(px,py,pz,(const float2*)table+(size_t)l*TSZ,a0,a1);
            else dense_point<54>(px,py,pz,(const float2*)table+(size_t)l*TSZ,a0,a1);
        } else {
            hash_point(px,py,pz,(float)kRes[l],(const float2*)table+(size_t)l*TSZ,a0,a1);
        }
        h[2*l+0] = a0; h[2*l+1] = a1;
    }

#pragma unroll
    for (int k = 0; k < 32; ++k) hS[k * 256 + t] = h[k];
    float h1[64];
#pragma unroll
    for (int j = 0; j < 64; ++j) h1[j] = 0.f;
    for (int k = 0; k < 32; ++k) {
        const float hk = hS[k * 256 + t];
        const float* __restrict__ Wr = W1 + k * 64;
#pragma unroll
        for (int q = 0; q < 16; ++q) {
            const float4 wv = *reinterpret_cast<const float4*>(Wr + 4*q);
            h1[4*q+0]=fmaf(hk,wv.x,h1[4*q+0]); h1[4*q+1]=fmaf(hk,wv.y,h1[4*q+1]);
            h1[4*q+2]=fmaf(hk,wv.z,h1[4*q+2]); h1[4*q+3]=fmaf(hk,wv.w,h1[4*q+3]);
        }
    }
    float h2[64];
#pragma unroll
    for (int j = 0; j < 64; ++j) h2[j] = 0.f;
#pragma unroll
    for (int half = 0; half < 2; ++half) {
#pragma unroll
        for (int k = 0; k < 32; ++k) hS[k * 256 + t] = fmaxf(h1[half*32+k], 0.f);
        for (int k = 0; k < 32; ++k) {
            const float hk = hS[k * 256 + t];
            const float* __restrict__ Wr = W2 + (half*32+k) * 64;
#pragma unroll
            for (int q = 0; q < 16; ++q) {
                const float4 wv = *reinterpret_cast<const float4*>(Wr + 4*q);
                h2[4*q+0]=fmaf(hk,wv.x,h2[4*q+0]); h2[4*q+1]=fmaf(hk,wv.y,h2[4*q+1]);
                h2[4*q+2]=fmaf(hk,wv.z,h2[4*q+2]); h2[4*q+3]=fmaf(hk,wv.w,h2[4*q+3]);
            }
        }
    }
    float h3[16];
#pragma unroll
    for (int j = 0; j < 16; ++j) h3[j] = 0.f;
#pragma unroll
    for (int half = 0; half < 2; ++half) {
#pragma unroll
        for (int k = 0; k < 32; ++k) hS[k * 256 + t] = fmaxf(h2[half*32+k], 0.f);
        for (int k = 0; k < 32; ++k) {
            const float hk = hS[k * 256 + t];
            const float* __restrict__ Wr = W3 + (half*32+k) * 16;
#pragma unroll
            for (int q = 0; q < 4; ++q) {
                const float4 wv = *reinterpret_cast<const float4*>(Wr + 4*q);
                h3[4*q+0]=fmaf(hk,wv.x,h3[4*q+0]); h3[4*q+1]=fmaf(hk,wv.y,h3[4*q+1]);
                h3[4*q+2]=fmaf(hk,wv.z,h3[4*q+2]); h3[4*q+3]=fmaf(hk,wv.w,h3[4*q+3]);
            }
        }
    }
    float4* __restrict__ o = reinterpret_cast<float4*>(out + (size_t)i * 16);
    o[0] = make_float4(h3[0],h3[1],h3[2],h3[3]);
    o[1] = make_float4(h3[4],h3[5],h3[6],h3[7]);
    o[2] = make_float4(h3[8],h3[9],h3[10],h3[11]);
    o[3] = make_float4(h3[12],h3[13],h3[14],h3[15]);
}

extern "C" void kernel_launch(void* const* d_in, const int* in_sizes, int n_in,
                              void* d_out, int out_size, void* d_ws, size_t ws_size,
                              hipStream_t stream) {
    const float* x     = (const float*)d_in[0];
    const float* table = (const float*)d_in[1];
    const float* W1    = (const float*)d_in[2];
    const float* W2    = (const float*)d_in[3];
    const float* W3    = (const float*)d_in[4];
    float* out = (float*)d_out;

    const int n = in_sizes[0] / 3;
    const size_t need = (size_t)n * 32 * sizeof(float);

    if (ws_size >= need) {
        float* hT = (float*)d_ws;                          // [32][n] feature-major
        const int chunks = (n + 1023) / 1024;
        for (int l = 4; l < 16; ++l)
            encode_hash_lvl<<<chunks, 256, 0, stream>>>(x, table, hT, n, l);
        encode_dense<<<(n + 255) / 256, 256, 0, stream>>>(x, table, hT, n);

        // A/B split: first half -> mlp_two (2 pts/thread), second half -> mlp_one
        const int m = (n / 2) & ~511;                      // multiple of 512
        if (m > 0)
            mlp_two<<<m / 512, 256, 0, stream>>>(hT, W1, W2, W3, out, n);
        mlp_one<<<(n - m + 255) / 256, 256, 0, stream>>>(hT, W1, W2, W3, out, n, m);
    } else {
        ngp_fused_kernel<<<(n + 255) / 256, 256, 0, stream>>>(x, table, W1, W2, W3, out, n);
    }
}